// Round 1
// baseline (536.716 us; speedup 1.0000x reference)
//
#include <hip/hip_runtime.h>
#include <math.h>

// Problem constants
#define BROWS 16384
#define N0    2048
#define NCLS  12
#define NCLU  24
#define NDIM  4
#define NCOL  348          // 12 + 288 + 48
#define NPAD  384          // padded column count (multiple of 64)

// ws float offsets
#define WP_OFF   0
#define WP_SIZE  (N0 * NPAD)                 // 786432 floats
#define BIAS_OFF (WP_OFF + WP_SIZE)
#define BIAS_SIZE NPAD
#define Y_OFF    (BIAS_OFF + BIAS_SIZE)
#define Y_SIZE   (BROWS * NPAD)              // 6291456 floats

// Output offsets (floats) in d_out: y0 [B,12] | y1_sel [B,24] | y2_sel [B,4] | Plc [B,24,12]
#define OUT0_OFF 0
#define OUT1_OFF (BROWS * NCLS)                       // 196608
#define OUT2_OFF (OUT1_OFF + BROWS * NCLU)            // 589824
#define OUT3_OFF (OUT2_OFF + BROWS * NDIM)            // 655360

// ---------------------------------------------------------------------------
// Kernel 1: repack weights into Wp[d][j] (K-major rows of the fused weight
// matrix, padded to 384 cols with zeros) and bias[j].
//   j in [0,12):    y0 class j            <- W_fc[d, j]
//   j in [12,300):  y1, j-12 = k*12+c     <- W_bin[c, d, k]
//   j in [300,348): y2, j-300 = n*12+c    <- W_res[c, d, n]
// ---------------------------------------------------------------------------
__global__ void jcp_repack(const float* __restrict__ W_fc, const float* __restrict__ b_fc,
                           const float* __restrict__ W_bin, const float* __restrict__ b_bin,
                           const float* __restrict__ W_res, const float* __restrict__ b_res,
                           float* __restrict__ ws) {
    int idx = blockIdx.x * blockDim.x + threadIdx.x;
    if (idx < N0 * NPAD) {
        int d = idx / NPAD;
        int j = idx - d * NPAD;
        float v = 0.0f;
        if (j < NCLS) {
            v = W_fc[d * NCLS + j];
        } else if (j < 12 + NCLU * NCLS) {
            int jj = j - 12;
            int k = jj / NCLS;
            int c = jj - k * NCLS;
            v = W_bin[((size_t)c * N0 + d) * NCLU + k];
        } else if (j < NCOL) {
            int jj = j - 300;
            int n = jj / NCLS;
            int c = jj - n * NCLS;
            v = W_res[((size_t)c * N0 + d) * NDIM + n];
        }
        ws[WP_OFF + idx] = v;
    }
    if (idx < NPAD) {
        int j = idx;
        float v = 0.0f;
        if (j < NCLS) {
            v = b_fc[j];
        } else if (j < 12 + NCLU * NCLS) {
            int jj = j - 12;
            int k = jj / NCLS;
            int c = jj - k * NCLS;
            v = b_bin[c * NCLU + k];
        } else if (j < NCOL) {
            int jj = j - 300;
            int n = jj / NCLS;
            int c = jj - n * NCLS;
            v = b_res[c * NDIM + n];
        }
        ws[BIAS_OFF + j] = v;
    }
}

// ---------------------------------------------------------------------------
// Kernel 2: fp32 SGEMM  Y[16384,384] = x[16384,2048] @ Wp[2048,384] + bias
// BM=64, BN=64, BK=16, 256 threads, 4x4 microtile per thread.
// ---------------------------------------------------------------------------
#define BM 64
#define BN 64
#define BK 16
#define LSTR 68   // LDS row stride (floats); pad 64->68 keeps 16B alignment

__global__ __launch_bounds__(256) void jcp_gemm(const float* __restrict__ x,
                                                const float* __restrict__ Wp,
                                                const float* __restrict__ bias,
                                                float* __restrict__ Y) {
    __shared__ float Xs[BK][LSTR];   // [k][m]
    __shared__ float Wsh[BK][LSTR];  // [k][n]

    const int tid = threadIdx.x;
    const int tx = tid & 15;   // n-direction (cols)
    const int ty = tid >> 4;   // m-direction (rows)
    const int jbase = blockIdx.x * BN;
    const int rbase = blockIdx.y * BM;

    float acc[4][4] = {};

    // Global staging thread mappings
    const int lxr = tid >> 2;          // 0..63: row within M-tile
    const int lxk = (tid & 3) * 4;     // 0,4,8,12: k0 within K-tile
    const int lwd = tid >> 4;          // 0..15: depth within K-tile
    const int lwj = (tid & 15) * 4;    // 0..60: col0 within N-tile

    const float* xg = x + (size_t)(rbase + lxr) * N0 + lxk;
    const float* wg = Wp + (size_t)lwd * NPAD + jbase + lwj;

    for (int kb = 0; kb < N0; kb += BK) {
        const float4 xv = *(const float4*)(xg + kb);
        const float4 wv = *(const float4*)(wg + (size_t)kb * NPAD);
        __syncthreads();   // previous iteration's LDS reads complete
        Xs[lxk + 0][lxr] = xv.x;
        Xs[lxk + 1][lxr] = xv.y;
        Xs[lxk + 2][lxr] = xv.z;
        Xs[lxk + 3][lxr] = xv.w;
        *(float4*)&Wsh[lwd][lwj] = wv;
        __syncthreads();

        #pragma unroll
        for (int kk = 0; kk < BK; ++kk) {
            const float4 av = *(const float4*)&Xs[kk][ty * 4];
            const float4 bv = *(const float4*)&Wsh[kk][tx * 4];
            const float a[4] = {av.x, av.y, av.z, av.w};
            const float b[4] = {bv.x, bv.y, bv.z, bv.w};
            #pragma unroll
            for (int i = 0; i < 4; ++i)
                #pragma unroll
                for (int j = 0; j < 4; ++j)
                    acc[i][j] = fmaf(a[i], b[j], acc[i][j]);
        }
    }

    // Epilogue: add bias, store float4 per row
    const int col0 = jbase + tx * 4;
    const float4 bv = *(const float4*)&bias[col0];
    #pragma unroll
    for (int i = 0; i < 4; ++i) {
        const int row = rbase + ty * 4 + i;
        float4 o;
        o.x = acc[i][0] + bv.x;
        o.y = acc[i][1] + bv.y;
        o.z = acc[i][2] + bv.z;
        o.w = acc[i][3] + bv.w;
        *(float4*)&Y[(size_t)row * NPAD + col0] = o;
    }
}

// ---------------------------------------------------------------------------
// Kernel 3: per-row head. Thread r handles row r.
//   Pc = softmax(y0); per-class cluster softmax stats; Plc = Pl*Pc;
//   joint argmax over flat (k*12+c) with first-occurrence tie-break;
//   gathers y1_sel, y2_sel; writes all 4 outputs.
// ---------------------------------------------------------------------------
__global__ void jcp_head(const float* __restrict__ Y, float* __restrict__ out) {
    const int r = blockIdx.x * blockDim.x + threadIdx.x;
    if (r >= BROWS) return;
    const float* y = Y + (size_t)r * NPAD;

    float* __restrict__ out0 = out + OUT0_OFF + (size_t)r * NCLS;
    float* __restrict__ out1 = out + OUT1_OFF + (size_t)r * NCLU;
    float* __restrict__ out2 = out + OUT2_OFF + (size_t)r * NDIM;
    float* __restrict__ out3 = out + OUT3_OFF + (size_t)r * (NCLU * NCLS);

    // category softmax
    float yv0[NCLS];
    float m0 = -INFINITY;
    #pragma unroll
    for (int c = 0; c < NCLS; ++c) {
        yv0[c] = y[c];
        m0 = fmaxf(m0, yv0[c]);
    }
    float Pc[NCLS];
    float s0 = 0.0f;
    #pragma unroll
    for (int c = 0; c < NCLS; ++c) {
        Pc[c] = expf(yv0[c] - m0);
        s0 += Pc[c];
    }
    const float inv0 = 1.0f / s0;
    #pragma unroll
    for (int c = 0; c < NCLS; ++c) Pc[c] *= inv0;

    // per-class cluster softmax stats (two passes; row data stays in L1)
    float mc[NCLS], rsc[NCLS];
    #pragma unroll
    for (int c = 0; c < NCLS; ++c) {
        float m = -INFINITY;
        for (int k = 0; k < NCLU; ++k) m = fmaxf(m, y[12 + k * NCLS + c]);
        float s = 0.0f;
        for (int k = 0; k < NCLU; ++k) s += expf(y[12 + k * NCLS + c] - m);
        mc[c] = m;
        rsc[c] = 1.0f / s;
    }

    // Plc + joint argmax (flat order k*12+c, strict > => first occurrence)
    float best = -INFINITY;
    int bi = 0;
    for (int k = 0; k < NCLU; ++k) {
        #pragma unroll
        for (int c = 0; c < NCLS; ++c) {
            const float p = expf(y[12 + k * NCLS + c] - mc[c]) * rsc[c] * Pc[c];
            out3[k * NCLS + c] = p;
            if (p > best) { best = p; bi = k * NCLS + c; }
        }
    }
    const int ic = bi % NCLS;

    // gathers + y0 out
    for (int k = 0; k < NCLU; ++k) out1[k] = y[12 + k * NCLS + ic];
    #pragma unroll
    for (int n = 0; n < NDIM; ++n) out2[n] = y[300 + n * NCLS + ic];
    #pragma unroll
    for (int c = 0; c < NCLS; ++c) out0[c] = yv0[c];
}

// ---------------------------------------------------------------------------
extern "C" void kernel_launch(void* const* d_in, const int* in_sizes, int n_in,
                              void* d_out, int out_size, void* d_ws, size_t ws_size,
                              hipStream_t stream) {
    const float* x     = (const float*)d_in[0];
    const float* W_fc  = (const float*)d_in[1];
    const float* b_fc  = (const float*)d_in[2];
    const float* W_bin = (const float*)d_in[3];
    const float* b_bin = (const float*)d_in[4];
    const float* W_res = (const float*)d_in[5];
    const float* b_res = (const float*)d_in[6];
    float* out = (float*)d_out;
    float* ws  = (float*)d_ws;

    // 1) repack weights + bias
    {
        const int total = N0 * NPAD;
        jcp_repack<<<(total + 255) / 256, 256, 0, stream>>>(W_fc, b_fc, W_bin, b_bin,
                                                            W_res, b_res, ws);
    }
    // 2) fused GEMM -> Y
    {
        dim3 grid(NPAD / BN, BROWS / BM);  // (6, 256)
        jcp_gemm<<<grid, 256, 0, stream>>>(x, ws + WP_OFF, ws + BIAS_OFF, ws + Y_OFF);
    }
    // 3) head
    {
        jcp_head<<<BROWS / 64, 64, 0, stream>>>(ws + Y_OFF, out);
    }
}

// Round 2
// 424.461 us; speedup vs baseline: 1.2645x; 1.2645x over previous
//
#include <hip/hip_runtime.h>
#include <math.h>

// Problem constants
#define BROWS 16384
#define N0    2048
#define NCLS  12
#define NCLU  24
#define NDIM  4
#define NCOL  348          // 12 + 288 + 48
#define NPAD  384          // padded fused-column count (24 MFMA col-tiles)

// Output offsets (floats): y0 [B,12] | y1_sel [B,24] | y2_sel [B,4] | Plc [B,24,12]
#define OUT0_OFF 0
#define OUT1_OFF (BROWS * NCLS)
#define OUT2_OFF (OUT1_OFF + BROWS * NCLU)
#define OUT3_OFF (OUT2_OFF + BROWS * NDIM)

typedef __attribute__((ext_vector_type(8))) short bf16x8;
typedef __attribute__((ext_vector_type(4))) float f32x4;
typedef unsigned short ushort_t;

// ---------------------------------------------------------------------------
// bf16 split helpers (RNE)
// ---------------------------------------------------------------------------
__device__ __forceinline__ unsigned short f2bf(float f) {
    unsigned u = __float_as_uint(f);
    u += 0x7fffu + ((u >> 16) & 1u);
    return (unsigned short)(u >> 16);
}
__device__ __forceinline__ float bf2f(unsigned short h) {
    return __uint_as_float(((unsigned)h) << 16);
}
__device__ __forceinline__ void cvt8(float4 a, float4 b, bf16x8& h, bf16x8& l) {
    float f[8] = {a.x, a.y, a.z, a.w, b.x, b.y, b.z, b.w};
    #pragma unroll
    for (int i = 0; i < 8; ++i) {
        unsigned short hi = f2bf(f[i]);
        h[i] = (short)hi;
        l[i] = (short)f2bf(f[i] - bf2f(hi));
    }
}

// ---------------------------------------------------------------------------
// Kernel 1: repack fused weight matrix into N-major bf16 hi/lo:
//   Wt_hi[j][d], Wt_lo[j][d]  (j = 0..383, d = 0..2047), plus fp32 bias[384].
//   j <12:        W_fc[d,j]
//   12<=j<300:    j-12 = k*12+c  -> W_bin[c,d,k]
//   300<=j<348:   j-300 = n*12+c -> W_res[c,d,n]
//   else 0 (pad)
// ---------------------------------------------------------------------------
__global__ void jcp_repack2(const float* __restrict__ W_fc, const float* __restrict__ b_fc,
                            const float* __restrict__ W_bin, const float* __restrict__ b_bin,
                            const float* __restrict__ W_res, const float* __restrict__ b_res,
                            ushort_t* __restrict__ Wh, ushort_t* __restrict__ Wl,
                            float* __restrict__ bias) {
    int idx = blockIdx.x * 256 + threadIdx.x;
    if (idx >= NPAD * N0) return;
    int j = idx >> 11;          // /2048
    int d = idx & 2047;
    float w = 0.0f;
    if (j < NCLS) {
        w = W_fc[d * NCLS + j];
    } else if (j < 12 + NCLU * NCLS) {
        int jj = j - 12;
        int k = jj / NCLS, c = jj - k * NCLS;
        w = W_bin[((size_t)c * N0 + d) * NCLU + k];
    } else if (j < NCOL) {
        int jj = j - 300;
        int n = jj / NCLS, c = jj - n * NCLS;
        w = W_res[((size_t)c * N0 + d) * NDIM + n];
    }
    unsigned short h = f2bf(w);
    Wh[idx] = h;
    Wl[idx] = f2bf(w - bf2f(h));

    if (idx < NPAD) {
        int jb = idx;
        float bv = 0.0f;
        if (jb < NCLS) {
            bv = b_fc[jb];
        } else if (jb < 12 + NCLU * NCLS) {
            int jj = jb - 12;
            int k = jj / NCLS, c = jj - k * NCLS;
            bv = b_bin[c * NCLU + k];
        } else if (jb < NCOL) {
            int jj = jb - 300;
            int n = jj / NCLS, c = jj - n * NCLS;
            bv = b_res[c * NDIM + n];
        }
        bias[jb] = bv;
    }
}

// ---------------------------------------------------------------------------
// Kernel 2: split-bf16 MFMA GEMM, no LDS, no barriers.
//   Y[16384,384] = x[16384,2048] @ W[2048,384] + bias
//   Block: 256 thr (4 waves), BM=32 rows, each wave owns 96 cols (6 tiles).
//   3-term split: hh + lh + hl per 16x16x32 MFMA tile. Register prefetch.
// ---------------------------------------------------------------------------
#define BMg 32

__global__ __launch_bounds__(256) void jcp_gemm_mfma(const float* __restrict__ x,
                                                     const ushort_t* __restrict__ Wh,
                                                     const ushort_t* __restrict__ Wl,
                                                     const float* __restrict__ bias,
                                                     float* __restrict__ Y) {
    const int tid  = threadIdx.x;
    const int wid  = tid >> 6;        // wave 0..3
    const int lane = tid & 63;
    const int quad = lane >> 4;       // 0..3
    const int l16  = lane & 15;       // 0..15
    const int rbase = blockIdx.x * BMg;
    const int jw    = wid * 96;

    f32x4 acc[2][6];
    #pragma unroll
    for (int i = 0; i < 2; ++i)
        #pragma unroll
        for (int j = 0; j < 6; ++j)
            acc[i][j] = f32x4{0.f, 0.f, 0.f, 0.f};

    // A: tile i rows rbase+16i+l16, k = kb + quad*8 .. +7  (8 consecutive fp32)
    const float* xA0 = x + (size_t)(rbase + l16) * N0 + quad * 8;
    const float* xA1 = xA0 + 16 * N0;
    // B: tile j row (jw+16j+l16) of Wt, k = kb + quad*8 .. +7 (8 consecutive bf16)
    const ushort_t* pWh = Wh + (size_t)(jw + l16) * N0 + quad * 8;
    const ushort_t* pWl = Wl + (size_t)(jw + l16) * N0 + quad * 8;
    const int TJ = 16 * N0;   // col-tile stride in elements

    // preload iteration 0
    float4 cA0a = *(const float4*)(xA0);
    float4 cA0b = *(const float4*)(xA0 + 4);
    float4 cA1a = *(const float4*)(xA1);
    float4 cA1b = *(const float4*)(xA1 + 4);
    bf16x8 cBh[6], cBl[6];
    #pragma unroll
    for (int j = 0; j < 6; ++j) {
        cBh[j] = *(const bf16x8*)(pWh + j * TJ);
        cBl[j] = *(const bf16x8*)(pWl + j * TJ);
    }

    for (int it = 0; it < N0 / 32; ++it) {
        const int kn = (it + 1) * 32;
        float4 nA0a, nA0b, nA1a, nA1b;
        bf16x8 nBh[6], nBl[6];
        if (it < N0 / 32 - 1) {
            nA0a = *(const float4*)(xA0 + kn);
            nA0b = *(const float4*)(xA0 + kn + 4);
            nA1a = *(const float4*)(xA1 + kn);
            nA1b = *(const float4*)(xA1 + kn + 4);
            #pragma unroll
            for (int j = 0; j < 6; ++j) {
                nBh[j] = *(const bf16x8*)(pWh + kn + j * TJ);
                nBl[j] = *(const bf16x8*)(pWl + kn + j * TJ);
            }
        }

        bf16x8 A0h, A0l, A1h, A1l;
        cvt8(cA0a, cA0b, A0h, A0l);
        cvt8(cA1a, cA1b, A1h, A1l);

        #pragma unroll
        for (int j = 0; j < 6; ++j) {
            acc[0][j] = __builtin_amdgcn_mfma_f32_16x16x32_bf16(A0h, cBh[j], acc[0][j], 0, 0, 0);
            acc[0][j] = __builtin_amdgcn_mfma_f32_16x16x32_bf16(A0l, cBh[j], acc[0][j], 0, 0, 0);
            acc[0][j] = __builtin_amdgcn_mfma_f32_16x16x32_bf16(A0h, cBl[j], acc[0][j], 0, 0, 0);
            acc[1][j] = __builtin_amdgcn_mfma_f32_16x16x32_bf16(A1h, cBh[j], acc[1][j], 0, 0, 0);
            acc[1][j] = __builtin_amdgcn_mfma_f32_16x16x32_bf16(A1l, cBh[j], acc[1][j], 0, 0, 0);
            acc[1][j] = __builtin_amdgcn_mfma_f32_16x16x32_bf16(A1h, cBl[j], acc[1][j], 0, 0, 0);
        }

        if (it < N0 / 32 - 1) {
            cA0a = nA0a; cA0b = nA0b; cA1a = nA1a; cA1b = nA1b;
            #pragma unroll
            for (int j = 0; j < 6; ++j) { cBh[j] = nBh[j]; cBl[j] = nBl[j]; }
        }
    }

    // Epilogue: C/D layout col = lane&15, row = quad*4 + reg
    #pragma unroll
    for (int j = 0; j < 6; ++j) {
        const int col = jw + 16 * j + l16;
        const float bj = bias[col];
        #pragma unroll
        for (int i = 0; i < 2; ++i) {
            float* yp = Y + (size_t)(rbase + 16 * i + quad * 4) * NPAD + col;
            yp[0 * NPAD] = acc[i][j][0] + bj;
            yp[1 * NPAD] = acc[i][j][1] + bj;
            yp[2 * NPAD] = acc[i][j][2] + bj;
            yp[3 * NPAD] = acc[i][j][3] + bj;
        }
    }
}

// ---------------------------------------------------------------------------
// Kernel 3: head, 16 lanes per row (lane = class c, lanes 12-15 idle).
//   256 thr/block -> 16 rows/block, grid 1024 (4096 waves device-wide).
// ---------------------------------------------------------------------------
__global__ __launch_bounds__(256) void jcp_head2(const float* __restrict__ Y,
                                                 float* __restrict__ out) {
    const int tid = threadIdx.x;
    const int grp = tid >> 4;
    const int c   = tid & 15;
    const int r   = blockIdx.x * 16 + grp;
    const bool on = (c < NCLS);
    const float* y = Y + (size_t)r * NPAD;

    // category softmax over 12 classes (cross-lane, width 16)
    float y0c = on ? y[c] : -INFINITY;
    float m0 = y0c;
    #pragma unroll
    for (int m = 8; m >= 1; m >>= 1) m0 = fmaxf(m0, __shfl_xor(m0, m, 16));
    float e0 = on ? expf(y0c - m0) : 0.0f;
    float s0 = e0;
    #pragma unroll
    for (int m = 8; m >= 1; m >>= 1) s0 += __shfl_xor(s0, m, 16);
    const float Pc = e0 / s0;

    // per-class cluster values (lane c owns class c, 24 strided loads —
    // coalesced across the 12 lanes of the group per k)
    float v[NCLU];
    float mc = -INFINITY;
    #pragma unroll
    for (int k = 0; k < NCLU; ++k) {
        v[k] = y[12 + k * NCLS + c];   // c in [12,16) reads in-row garbage, unused
        mc = fmaxf(mc, v[k]);
    }
    float sc = 0.0f;
    #pragma unroll
    for (int k = 0; k < NCLU; ++k) sc += expf(v[k] - mc);
    const float rs = Pc / sc;

    // Plc write + per-class best (strict >, ascending k = first occurrence)
    float* o3 = out + OUT3_OFF + (size_t)r * (NCLU * NCLS);
    float best = -INFINITY;
    int bk = 0;
    #pragma unroll
    for (int k = 0; k < NCLU; ++k) {
        const float p = expf(v[k] - mc) * rs;
        if (on) o3[k * NCLS + c] = p;
        if (p > best) { best = p; bk = k; }
    }
    int flat = bk * NCLS + c;
    if (!on) { best = -INFINITY; flat = 1 << 30; }

    // cross-lane joint argmax: larger p wins; tie -> smaller flat index
    #pragma unroll
    for (int m = 8; m >= 1; m >>= 1) {
        const float op = __shfl_xor(best, m, 16);
        const int   of = __shfl_xor(flat, m, 16);
        if (op > best || (op == best && of < flat)) { best = op; flat = of; }
    }
    const int ic = flat % NCLS;   // flat = k*12 + c

    if (on) out[OUT0_OFF + (size_t)r * NCLS + c] = y0c;
    if (c == ic) {
        float* o1 = out + OUT1_OFF + (size_t)r * NCLU;
        #pragma unroll
        for (int k = 0; k < NCLU; ++k) o1[k] = v[k];
        float* o2 = out + OUT2_OFF + (size_t)r * NDIM;
        #pragma unroll
        for (int n = 0; n < NDIM; ++n) o2[n] = y[300 + n * NCLS + ic];
    }
}

// ---------------------------------------------------------------------------
extern "C" void kernel_launch(void* const* d_in, const int* in_sizes, int n_in,
                              void* d_out, int out_size, void* d_ws, size_t ws_size,
                              hipStream_t stream) {
    const float* x     = (const float*)d_in[0];
    const float* W_fc  = (const float*)d_in[1];
    const float* b_fc  = (const float*)d_in[2];
    const float* W_bin = (const float*)d_in[3];
    const float* b_bin = (const float*)d_in[4];
    const float* W_res = (const float*)d_in[5];
    const float* b_res = (const float*)d_in[6];
    float* out = (float*)d_out;

    // ws layout
    ushort_t* Wh   = (ushort_t*)d_ws;                  // 384*2048 bf16
    ushort_t* Wl   = Wh + NPAD * N0;                   // 384*2048 bf16
    float*    bias = (float*)(Wl + NPAD * N0);         // 384 fp32
    float*    Yb   = bias + NPAD;                      // 16384*384 fp32

    // 1) repack + split weights
    jcp_repack2<<<(NPAD * N0 + 255) / 256, 256, 0, stream>>>(W_fc, b_fc, W_bin, b_bin,
                                                             W_res, b_res, Wh, Wl, bias);
    // 2) MFMA GEMM
    jcp_gemm_mfma<<<BROWS / BMg, 256, 0, stream>>>(x, Wh, Wl, bias, Yb);
    // 3) head
    jcp_head2<<<BROWS / 16, 256, 0, stream>>>(Yb, out);
}